// Round 1
// baseline (1067.899 us; speedup 1.0000x reference)
//
#include <hip/hip_runtime.h>

// Dims (fixed for this problem instance; start_pos read from device)
#define BATCH 32
#define DMODEL 4096
#define NH 32
#define NKV 8
#define DH 128
#define TCACHE 4096
#define NCOLS_QKV 6144   // 4096 q + 1024 k + 1024 v

// ---------------------------------------------------------------------------
// Kernel 1: QKV projection, split-K partials.
// grid (24, nchunk), block 256. Each block: 256 cols x 32 batches x dchunk K.
// Thread (tx,ty): cols col4..col4+3 (float4), batches ty*8..ty*8+7.
// ---------------------------------------------------------------------------
__global__ __launch_bounds__(256) void qkv_partial(
    const float* __restrict__ x, const float* __restrict__ wq,
    const float* __restrict__ wk, const float* __restrict__ wv,
    float* __restrict__ pbuf, int dchunk) {
  __shared__ float xs[BATCH * 128];
  const int tid = threadIdx.x, tx = tid & 63, ty = tid >> 6;
  const int bx = blockIdx.x, by = blockIdx.y;

  const float* W;
  int ldw, colw, colp;
  if (bx < 16)      { W = wq; ldw = 4096; colw = bx * 256 + tx * 4;        colp = colw; }
  else if (bx < 20) { W = wk; ldw = 1024; colw = (bx - 16) * 256 + tx * 4; colp = 4096 + colw; }
  else              { W = wv; ldw = 1024; colw = (bx - 20) * 256 + tx * 4; colp = 5120 + colw; }

  float4 acc[8];
#pragma unroll
  for (int i = 0; i < 8; ++i) acc[i] = make_float4(0.f, 0.f, 0.f, 0.f);

  const int d0 = by * dchunk;
  for (int s = 0; s < dchunk; s += 128) {
    __syncthreads();
    for (int i = tid; i < BATCH * 128; i += 256)
      xs[i] = x[(size_t)(i >> 7) * DMODEL + d0 + s + (i & 127)];
    __syncthreads();

    const float* wrow = W + (size_t)(d0 + s) * ldw + colw;
#pragma unroll 4
    for (int dd = 0; dd < 128; ++dd) {
      float4 w4 = *(const float4*)wrow;
      wrow += ldw;
#pragma unroll
      for (int i = 0; i < 8; ++i) {
        float xv = xs[(ty * 8 + i) * 128 + dd];
        acc[i].x += xv * w4.x; acc[i].y += xv * w4.y;
        acc[i].z += xv * w4.z; acc[i].w += xv * w4.w;
      }
    }
  }
#pragma unroll
  for (int i = 0; i < 8; ++i) {
    int b = ty * 8 + i;
    *(float4*)&pbuf[((size_t)by * BATCH + b) * NCOLS_QKV + colp] = acc[i];
  }
}

// ---------------------------------------------------------------------------
// Kernel 2: sum split-K partials + apply rotation.
// grid (48, 32): x = slot (0..31 q-head, 32..39 k-head, 40..47 v-head), y = b.
// block 128 (one thread per output element e).
// ---------------------------------------------------------------------------
__global__ __launch_bounds__(128) void rot_combine(
    const float* __restrict__ pbuf, const float* __restrict__ rot,
    float* __restrict__ q_ws, float* __restrict__ k_ws, float* __restrict__ v_ws,
    int nc) {
  __shared__ float xvec[DH];
  const int slot = blockIdx.x, b = blockIdx.y, e = threadIdx.x;

  int colbase;
  if (slot < 32)      colbase = slot * DH;
  else if (slot < 40) colbase = 4096 + (slot - 32) * DH;
  else                colbase = 5120 + (slot - 40) * DH;

  float s = 0.f;
  for (int c = 0; c < nc; ++c)
    s += pbuf[((size_t)c * BATCH + b) * NCOLS_QKV + colbase + e];

  if (slot >= 40) {  // v: no rotation
    v_ws[(b * NKV + slot - 40) * DH + e] = s;
    return;
  }
  xvec[e] = s;
  __syncthreads();

  const float* rb = rot + (size_t)b * DH * DH + e;
  float o = 0.f;
#pragma unroll 8
  for (int d = 0; d < DH; ++d) o += xvec[d] * rb[(size_t)d * DH];

  if (slot < 32) q_ws[(b * NH + slot) * DH + e] = o;
  else           k_ws[(b * NKV + slot - 32) * DH + e] = o;
}

// ---------------------------------------------------------------------------
// Kernel 3: attention decode. grid (NKV, BATCH), block 256 (4 waves).
// Phase 1: scores (4 q-heads share one K stream) -> LDS; softmax; Phase 2: PV.
// ---------------------------------------------------------------------------
__device__ __forceinline__ void dot128(const float* __restrict__ krp,
                                       const float* __restrict__ qhp,
                                       float& a0, float& a1, float& a2, float& a3) {
  const float4* kr = (const float4*)krp;
  const float4* q4 = (const float4*)qhp;
  a0 = a1 = a2 = a3 = 0.f;
#pragma unroll 8
  for (int c = 0; c < 32; ++c) {
    float4 kk = kr[c];
    float4 qa = q4[c], qb = q4[32 + c], qc = q4[64 + c], qd = q4[96 + c];
    a0 += kk.x * qa.x + kk.y * qa.y + kk.z * qa.z + kk.w * qa.w;
    a1 += kk.x * qb.x + kk.y * qb.y + kk.z * qb.z + kk.w * qb.w;
    a2 += kk.x * qc.x + kk.y * qc.y + kk.z * qc.z + kk.w * qc.w;
    a3 += kk.x * qd.x + kk.y * qd.y + kk.z * qd.z + kk.w * qd.w;
  }
}

__global__ __launch_bounds__(256) void attn_kernel(
    const float* __restrict__ q_ws, const float* __restrict__ k_ws,
    const float* __restrict__ v_ws, const float* __restrict__ keys,
    const float* __restrict__ values, const float* __restrict__ mask,
    const int* __restrict__ sp_ptr, float* __restrict__ out_ws) {
  __shared__ float sc[4 * TCACHE];   // 64 KB scores/probs
  __shared__ float qh[4 * DH];
  __shared__ float kn[DH], vn[DH];
  __shared__ float red[16];
  __shared__ float mg[4], il[4];
  __shared__ float op[4 * 4 * DH];   // per-wave PV partials

  const int kv = blockIdx.x, b = blockIdx.y, tid = threadIdx.x;
  const int lane = tid & 63, w = tid >> 6;
  const int sp = *sp_ptr;

  for (int i = tid; i < 4 * DH; i += 256)
    qh[i] = q_ws[(size_t)(b * NH + kv * 4) * DH + i] * 0.08838834764831845f;
  if (tid < 128)      kn[tid] = k_ws[(b * NKV + kv) * DH + tid];
  else                vn[tid - 128] = v_ws[(b * NKV + kv) * DH + (tid - 128)];
  __syncthreads();

  const size_t kvbase = (size_t)(b * NKV + kv) << 19;  // * TCACHE * DH
  const size_t mb0 = ((size_t)(kv * 4 + 0) * BATCH + b) << 12;
  const size_t mb1 = ((size_t)(kv * 4 + 1) * BATCH + b) << 12;
  const size_t mb2 = ((size_t)(kv * 4 + 2) * BATCH + b) << 12;
  const size_t mb3 = ((size_t)(kv * 4 + 3) * BATCH + b) << 12;

  // ---- phase 1: scores for t in [0, sp) from cache ----
  for (int t = tid; t < sp; t += 256) {
    float a0, a1, a2, a3;
    dot128(keys + kvbase + ((size_t)t << 7), qh, a0, a1, a2, a3);
    sc[t]              = a0 + mask[mb0 + t];
    sc[TCACHE + t]     = a1 + mask[mb1 + t];
    sc[2 * TCACHE + t] = a2 + mask[mb2 + t];
    sc[3 * TCACHE + t] = a3 + mask[mb3 + t];
  }
  // t == sp uses the freshly projected (rotated) k
  if (tid == (sp & 255)) {
    float a0, a1, a2, a3;
    dot128(kn, qh, a0, a1, a2, a3);
    sc[sp]              = a0 + mask[mb0 + sp];
    sc[TCACHE + sp]     = a1 + mask[mb1 + sp];
    sc[2 * TCACHE + sp] = a2 + mask[mb2 + sp];
    sc[3 * TCACHE + sp] = a3 + mask[mb3 + sp];
  }
  __syncthreads();

  // ---- softmax: max ----
  float lm0 = -3.4e38f, lm1 = -3.4e38f, lm2 = -3.4e38f, lm3 = -3.4e38f;
  for (int t = tid; t <= sp; t += 256) {
    lm0 = fmaxf(lm0, sc[t]);
    lm1 = fmaxf(lm1, sc[TCACHE + t]);
    lm2 = fmaxf(lm2, sc[2 * TCACHE + t]);
    lm3 = fmaxf(lm3, sc[3 * TCACHE + t]);
  }
#pragma unroll
  for (int off = 32; off > 0; off >>= 1) {
    lm0 = fmaxf(lm0, __shfl_down(lm0, off, 64));
    lm1 = fmaxf(lm1, __shfl_down(lm1, off, 64));
    lm2 = fmaxf(lm2, __shfl_down(lm2, off, 64));
    lm3 = fmaxf(lm3, __shfl_down(lm3, off, 64));
  }
  if (lane == 0) { red[w * 4] = lm0; red[w * 4 + 1] = lm1; red[w * 4 + 2] = lm2; red[w * 4 + 3] = lm3; }
  __syncthreads();
  if (tid < 4)
    mg[tid] = fmaxf(fmaxf(red[tid], red[4 + tid]), fmaxf(red[8 + tid], red[12 + tid]));
  __syncthreads();

  // ---- softmax: exp + sum (probs written back into sc) ----
  const float m0 = mg[0], m1 = mg[1], m2 = mg[2], m3 = mg[3];
  float s0 = 0.f, s1 = 0.f, s2 = 0.f, s3 = 0.f;
  for (int t = tid; t <= sp; t += 256) {
    float e0 = __expf(sc[t] - m0);              sc[t] = e0;              s0 += e0;
    float e1 = __expf(sc[TCACHE + t] - m1);     sc[TCACHE + t] = e1;     s1 += e1;
    float e2 = __expf(sc[2 * TCACHE + t] - m2); sc[2 * TCACHE + t] = e2; s2 += e2;
    float e3 = __expf(sc[3 * TCACHE + t] - m3); sc[3 * TCACHE + t] = e3; s3 += e3;
  }
#pragma unroll
  for (int off = 32; off > 0; off >>= 1) {
    s0 += __shfl_down(s0, off, 64);
    s1 += __shfl_down(s1, off, 64);
    s2 += __shfl_down(s2, off, 64);
    s3 += __shfl_down(s3, off, 64);
  }
  if (lane == 0) { red[w * 4] = s0; red[w * 4 + 1] = s1; red[w * 4 + 2] = s2; red[w * 4 + 3] = s3; }
  __syncthreads();
  if (tid < 4)
    il[tid] = 1.0f / (red[tid] + red[4 + tid] + red[8 + tid] + red[12 + tid]);
  __syncthreads();

  // ---- phase 2: PV. Each wave owns a contiguous t-quarter; coalesced V rows ----
  const int d2 = lane * 2;
  const int cnt = (sp + 4) >> 2;           // ceil((sp+1)/4)
  const int t0 = w * cnt;
  int t1 = t0 + cnt; if (t1 > sp + 1) t1 = sp + 1;
  const int tg = (t1 < sp) ? t1 : sp;      // global part: [t0, tg)

  float ox0 = 0.f, oy0 = 0.f, ox1 = 0.f, oy1 = 0.f;
  float ox2 = 0.f, oy2 = 0.f, ox3 = 0.f, oy3 = 0.f;
#pragma unroll 4
  for (int t = t0; t < tg; ++t) {
    float2 vv = *(const float2*)(values + kvbase + ((size_t)t << 7) + d2);
    float p0 = sc[t], p1 = sc[TCACHE + t], p2 = sc[2 * TCACHE + t], p3 = sc[3 * TCACHE + t];
    ox0 += p0 * vv.x; oy0 += p0 * vv.y;
    ox1 += p1 * vv.x; oy1 += p1 * vv.y;
    ox2 += p2 * vv.x; oy2 += p2 * vv.y;
    ox3 += p3 * vv.x; oy3 += p3 * vv.y;
  }
  if (sp >= t0 && sp < t1) {               // new-token row from LDS
    float vx = vn[d2], vy = vn[d2 + 1];
    float p0 = sc[sp], p1 = sc[TCACHE + sp], p2 = sc[2 * TCACHE + sp], p3 = sc[3 * TCACHE + sp];
    ox0 += p0 * vx; oy0 += p0 * vy;
    ox1 += p1 * vx; oy1 += p1 * vy;
    ox2 += p2 * vx; oy2 += p2 * vy;
    ox3 += p3 * vx; oy3 += p3 * vy;
  }
  *(float2*)&op[(w * 4 + 0) * DH + d2] = make_float2(ox0, oy0);
  *(float2*)&op[(w * 4 + 1) * DH + d2] = make_float2(ox1, oy1);
  *(float2*)&op[(w * 4 + 2) * DH + d2] = make_float2(ox2, oy2);
  *(float2*)&op[(w * 4 + 3) * DH + d2] = make_float2(ox3, oy3);
  __syncthreads();

  // cross-wave reduce; thread -> (g = w, d2)
  const int g = w;
  float r0 = op[g * DH + d2]     + op[(4 + g) * DH + d2]     + op[(8 + g) * DH + d2]     + op[(12 + g) * DH + d2];
  float r1 = op[g * DH + d2 + 1] + op[(4 + g) * DH + d2 + 1] + op[(8 + g) * DH + d2 + 1] + op[(12 + g) * DH + d2 + 1];
  float s = il[g];
  *(float2*)&out_ws[(size_t)(b * NH + kv * 4 + g) * DH + d2] = make_float2(r0 * s, r1 * s);
}

// ---------------------------------------------------------------------------
// Kernel 4: output projection (out_ws[32][4096] @ wo[4096][4096]), split-K.
// grid (16, nchunk), block 256.
// ---------------------------------------------------------------------------
__global__ __launch_bounds__(256) void out_partial(
    const float* __restrict__ xin, const float* __restrict__ wo,
    float* __restrict__ pbuf, int dchunk) {
  __shared__ float xs[BATCH * 128];
  const int tid = threadIdx.x, tx = tid & 63, ty = tid >> 6;
  const int bx = blockIdx.x, by = blockIdx.y;
  const int col = bx * 256 + tx * 4;

  float4 acc[8];
#pragma unroll
  for (int i = 0; i < 8; ++i) acc[i] = make_float4(0.f, 0.f, 0.f, 0.f);

  const int d0 = by * dchunk;
  for (int s = 0; s < dchunk; s += 128) {
    __syncthreads();
    for (int i = tid; i < BATCH * 128; i += 256)
      xs[i] = xin[(size_t)(i >> 7) * DMODEL + d0 + s + (i & 127)];
    __syncthreads();

    const float* wrow = wo + (size_t)(d0 + s) * DMODEL + col;
#pragma unroll 4
    for (int dd = 0; dd < 128; ++dd) {
      float4 w4 = *(const float4*)wrow;
      wrow += DMODEL;
#pragma unroll
      for (int i = 0; i < 8; ++i) {
        float xv = xs[(ty * 8 + i) * 128 + dd];
        acc[i].x += xv * w4.x; acc[i].y += xv * w4.y;
        acc[i].z += xv * w4.z; acc[i].w += xv * w4.w;
      }
    }
  }
#pragma unroll
  for (int i = 0; i < 8; ++i) {
    int b = ty * 8 + i;
    *(float4*)&pbuf[((size_t)by * BATCH + b) * DMODEL + col] = acc[i];
  }
}

// ---------------------------------------------------------------------------
// Kernel 5: reduce split-K partials into d_out.
// ---------------------------------------------------------------------------
__global__ __launch_bounds__(256) void reduce_out(
    const float* __restrict__ pbuf, float* __restrict__ out, int nc) {
  const int i = blockIdx.x * 256 + threadIdx.x;  // 131072 outputs
  const int b = i >> 12, e = i & 4095;
  float s = 0.f;
  for (int c = 0; c < nc; ++c)
    s += pbuf[((size_t)c * BATCH + b) * DMODEL + e];
  out[i] = s;
}

// ---------------------------------------------------------------------------
extern "C" void kernel_launch(void* const* d_in, const int* in_sizes, int n_in,
                              void* d_out, int out_size, void* d_ws, size_t ws_size,
                              hipStream_t stream) {
  const float* x      = (const float*)d_in[0];
  const float* wq     = (const float*)d_in[1];
  const float* wk     = (const float*)d_in[2];
  const float* wv     = (const float*)d_in[3];
  const float* wo     = (const float*)d_in[4];
  const float* rot    = (const float*)d_in[5];
  const float* mask   = (const float*)d_in[6];
  const float* keys   = (const float*)d_in[7];
  const float* values = (const float*)d_in[8];
  const int*   sp     = (const int*)d_in[9];
  float* out = (float*)d_out;
  float* ws  = (float*)d_ws;

  // aux buffers: q (131072) + k (32768) + v (32768) + attn out (131072)
  const size_t AUXF = 131072 + 32768 + 32768 + 131072;
  size_t wsf = ws_size / sizeof(float);

  int cA = 32;
  while (cA > 1 && (size_t)cA * (BATCH * NCOLS_QKV) + AUXF > wsf) cA >>= 1;
  int cD = 32;
  while (cD > 1 && (size_t)cD * (BATCH * DMODEL) + AUXF > wsf) cD >>= 1;

  size_t pmax = (size_t)cA * (BATCH * NCOLS_QKV);
  if ((size_t)cD * (BATCH * DMODEL) > pmax) pmax = (size_t)cD * (BATCH * DMODEL);

  float* pbuf   = ws;
  float* q_ws   = ws + pmax;
  float* k_ws   = q_ws + 131072;
  float* v_ws   = k_ws + 32768;
  float* out_ws = v_ws + 32768;

  qkv_partial<<<dim3(24, cA), 256, 0, stream>>>(x, wq, wk, wv, pbuf, DMODEL / cA);
  rot_combine<<<dim3(48, BATCH), 128, 0, stream>>>(pbuf, rot, q_ws, k_ws, v_ws, cA);
  attn_kernel<<<dim3(NKV, BATCH), 256, 0, stream>>>(q_ws, k_ws, v_ws, keys, values, mask, sp, out_ws);
  out_partial<<<dim3(16, cD), 256, 0, stream>>>(out_ws, wo, pbuf, DMODEL / cD);
  reduce_out<<<dim3(512), 256, 0, stream>>>(pbuf, out, cD);
}